// Round 6
// baseline (100.854 us; speedup 1.0000x reference)
//
#include <hip/hip_runtime.h>
#include <hip/hip_fp16.h>

#define G_   5000
#define B_   128
#define S_   32
#define NTH  192      // 3 waves
#define GPB  157      // ceil(5000/32) g's per block
#define NCHUNK 32     // 32 chunks * 64 b-pairs = 2048 blocks = exactly 8/CU (LDS-cap)

union H2F { __half2 h2; float f; };
__device__ __forceinline__ float h2_as_f(__half2 h) { H2F u; u.h2 = h; return u.f; }
__device__ __forceinline__ __half2 f_as_h2(float f) { H2F u; u.f = f; return u.h2; }

// ---------------- main clause evaluation ---------------------------------------
// Block: 192 threads; owns 2 consecutive batch rows (blockIdx.y) and a chunk of
// 157 g's (blockIdx.x). x rows quantized to fp16, pair-interleaved in LDS
// (20,000 B): xi2[i] = half2(x[b0][i], x[b0+1][i]). One ds_read_b32 serves 2
// outputs. 20 KB LDS -> 8 blocks/CU -> 24 waves/CU (6/SIMD) for latency hiding
// (R5 had only 10 waves/CU; the gather chain was latency-exposed).
// fp16 error: body rel err <= ~7*2^-11 = 3.4e-3 (convex-combination bound
// through logsumexp); measured absmax 3.9e-3 vs threshold 1.94e-2.
__global__ __launch_bounds__(NTH, 6)
void clause_main(const float* __restrict__ x,
                 const int*  __restrict__ idx,   // harness delivers int64 ref idx as int32
                 float* __restrict__ out,
                 int*   __restrict__ wsmax) {
    __shared__ __half xi[G_ * 2];         // 20,000 B
    __shared__ float red[NTH / 64];

    const int tid = threadIdx.x;
    const int b0  = blockIdx.y * 2;

    // ---- stage 2 x-rows -> fp16 pair-interleaved; one ds_write_b128 / 4 cols ----
    const float4* r0 = (const float4*)(x + (size_t)(b0 + 0) * G_);
    const float4* r1 = (const float4*)(x + (size_t)(b0 + 1) * G_);  // 5000%4==0
    float4* xi4 = (float4*)xi;
    for (int i = tid; i < G_ / 4; i += NTH) {   // 1250 iters total
        float4 a = r0[i], b = r1[i];
        float4 w;
        w.x = h2_as_f(__floats2half2_rn(a.x, b.x));
        w.y = h2_as_f(__floats2half2_rn(a.y, b.y));
        w.z = h2_as_f(__floats2half2_rn(a.z, b.z));
        w.w = h2_as_f(__floats2half2_rn(a.w, b.w));
        xi4[i] = w;
    }
    __syncthreads();

    const int g = blockIdx.x * GPB + tid;
    const bool active = (tid < GPB) && (g < G_);
    const float* xif = (const float*)xi;    // one float = half2 = both batches of col i
    float m = 0.0f;

    if (active) {
        // gamma*lse(body/gamma) = 0.15 + 0.01*ln(sum_s exp(100*body_s - 15))
        // body in (0,1]: term <= e^85, 32*e^85 ~ 2.6e38 < FLT_MAX; term >= e^-15.
        float acc0 = 0.0f, acc1 = 0.0f;
        const int4* ip = ((const int4*)idx) + (size_t)g * S_;
        #pragma unroll 4
        for (int s = 0; s < S_; ++s) {
            int4 id = ip[s];
            float w0 = xif[id.x];
            float w1 = xif[id.y];
            float w2 = xif[id.z];
            float w3 = xif[id.w];
            __half2 p = __hmul2(__hmul2(f_as_h2(w0), f_as_h2(w1)),
                                __hmul2(f_as_h2(w2), f_as_h2(w3)));
            float2 b01 = __half22float2(p);
            acc0 += __expf(fmaf(b01.x, 100.0f, -15.0f));
            acc1 += __expf(fmaf(b01.y, 100.0f, -15.0f));
        }
        float o0 = fmaf(0.01f, __logf(acc0), 0.15f);
        float o1 = fmaf(0.01f, __logf(acc1), 0.15f);
        out[(size_t)(b0 + 0) * G_ + g] = o0;
        out[(size_t)(b0 + 1) * G_ + g] = o1;
        m = fmaxf(o0, o1);
    }

    // ---- block max -> global atomic (positive floats: int-bit max == float max) ----
    #pragma unroll
    for (int off = 32; off >= 1; off >>= 1)
        m = fmaxf(m, __shfl_down(m, off));
    if ((tid & 63) == 0) red[tid >> 6] = m;
    __syncthreads();
    if (tid == 0) {
        float mm = red[0];
        #pragma unroll
        for (int w = 1; w < NTH / 64; ++w) mm = fmaxf(mm, red[w]);
        atomicMax(wsmax, __float_as_int(mm));
    }
}

// ---------------- conditional global-max normalization --------------------------
__global__ void norm_out(float* __restrict__ out, const int* __restrict__ wsmax, int n4) {
    int i = blockIdx.x * blockDim.x + threadIdx.x;
    float mv = __int_as_float(*wsmax);
    float s  = (mv > 1.0f) ? (1.0f / mv) : 1.0f;
    if (i < n4) {
        float4 v = ((float4*)out)[i];
        v.x *= s; v.y *= s; v.z *= s; v.w *= s;
        ((float4*)out)[i] = v;
    }
}

// ---------------- launcher ------------------------------------------------------
extern "C" void kernel_launch(void* const* d_in, const int* in_sizes, int n_in,
                              void* d_out, int out_size, void* d_ws, size_t ws_size,
                              hipStream_t stream) {
    const float* x   = (const float*)d_in[0];
    const int*   idx = (const int*)d_in[1];
    float* out = (float*)d_out;
    int* wsmax = (int*)d_ws;

    // zero the atomic-max cell (d_ws is re-poisoned 0xAA each replay)
    hipMemsetAsync(wsmax, 0, sizeof(int), stream);

    dim3 grid(NCHUNK, B_ / 2);
    clause_main<<<grid, NTH, 0, stream>>>(x, idx, out, wsmax);

    const int n4 = (B_ * G_) / 4;             // 160,000
    norm_out<<<(n4 + 255) / 256, 256, 0, stream>>>(out, wsmax, n4);
}

// Round 8
// 87.463 us; speedup vs baseline: 1.1531x; 1.1531x over previous
//
#include <hip/hip_runtime.h>
#include <hip/hip_fp16.h>

#define G_   5000
#define B_   128
#define S_   32
#define NTH  192      // 3 waves
#define GPB  157      // ceil(5000/32) g's per block
#define NCHUNK 32     // grid (32, 32) = 1024 blocks = exactly 4/CU (40KB LDS cap)

union H2F { __half2 h2; float f; };
__device__ __forceinline__ float h2_as_f(__half2 h) { H2F u; u.h2 = h; return u.f; }
__device__ __forceinline__ __half2 f_as_h2(float f) { H2F u; u.f = f; return u.h2; }

// ---------------- main clause evaluation ---------------------------------------
// Block: 192 threads; owns 4 consecutive batch rows (blockIdx.y) and 157 g's
// (blockIdx.x). x rows quantized to fp16, 4-batch-interleaved in LDS (40,000 B):
// xi[4*i+j] = (half)x[b0+j][i]; one ds_read_b64 serves 4 outputs (320K wave
// gathers total — measured packing: P=2@24w/CU=45us > P=4@10w/CU=~33us).
// Grid gives 4 blocks/CU (R5 flaw was 2/CU) = 12 waves/CU for latency hiding.
// exp via native exp2: exp(100b-15) = exp2(fma(b,144.269504,-21.6404)).
// fp16 error: body rel err <= ~3.4e-3, convex-combination through logsumexp;
// measured absmax 3.9e-3 vs threshold 1.94e-2.
__global__ __launch_bounds__(NTH, 3)
void clause_main(const float* __restrict__ x,
                 const int*  __restrict__ idx,   // harness delivers int64 ref idx as int32
                 float* __restrict__ out,
                 int*   __restrict__ wsmax) {
    __shared__ __half xi[G_ * 4];         // 40,000 B
    __shared__ float red[NTH / 64];

    const int tid = threadIdx.x;
    const int b0  = blockIdx.y * 4;

    // ---- stage 4 x-rows -> fp16, interleaved; one ds_write_b128 per 2 columns ----
    const float2* r0 = (const float2*)(x + (size_t)(b0 + 0) * G_);
    const float2* r1 = (const float2*)(x + (size_t)(b0 + 1) * G_);
    const float2* r2 = (const float2*)(x + (size_t)(b0 + 2) * G_);
    const float2* r3 = (const float2*)(x + (size_t)(b0 + 3) * G_);
    float4* xi4 = (float4*)xi;
    for (int i = tid; i < G_ / 2; i += NTH) {   // 2500 iters / 192 thr = 14 per thread
        float2 a0 = r0[i], a1 = r1[i], a2 = r2[i], a3 = r3[i];
        float4 w;
        w.x = h2_as_f(__floats2half2_rn(a0.x, a1.x));   // col 2i,   batches 0,1
        w.y = h2_as_f(__floats2half2_rn(a2.x, a3.x));   // col 2i,   batches 2,3
        w.z = h2_as_f(__floats2half2_rn(a0.y, a1.y));   // col 2i+1, batches 0,1
        w.w = h2_as_f(__floats2half2_rn(a2.y, a3.y));   // col 2i+1, batches 2,3
        xi4[i] = w;
    }
    __syncthreads();

    const int g = blockIdx.x * GPB + tid;
    const bool active = (tid < GPB) && (g < G_);
    const float2* xi2 = (const float2*)xi;   // one float2 = 4 halves = 4 batches of col i
    float m = 0.0f;

    if (active) {
        // gamma*lse(body/gamma) = 0.15 + 0.01*ln(sum_s exp(100*body_s - 15))
        // body in (0,1]: term <= e^85 => sum <= 32*e^85 ~ 2.6e38 < FLT_MAX.
        float acc0 = 0.0f, acc1 = 0.0f, acc2 = 0.0f, acc3 = 0.0f;
        const int4* ip = ((const int4*)idx) + (size_t)g * S_;
        #pragma unroll 8
        for (int s = 0; s < S_; ++s) {
            int4 id = ip[s];
            float2 w0 = xi2[id.x];
            float2 w1 = xi2[id.y];
            float2 w2 = xi2[id.z];
            float2 w3 = xi2[id.w];
            __half2 lo = __hmul2(__hmul2(f_as_h2(w0.x), f_as_h2(w1.x)),
                                 __hmul2(f_as_h2(w2.x), f_as_h2(w3.x)));
            __half2 hi = __hmul2(__hmul2(f_as_h2(w0.y), f_as_h2(w1.y)),
                                 __hmul2(f_as_h2(w2.y), f_as_h2(w3.y)));
            float2 b01 = __half22float2(lo);
            float2 b23 = __half22float2(hi);
            // exp(100*b-15) = 2^(b*144.269504 - 21.640425)
            acc0 += exp2f(fmaf(b01.x, 144.2695041f, -21.64042561f));
            acc1 += exp2f(fmaf(b01.y, 144.2695041f, -21.64042561f));
            acc2 += exp2f(fmaf(b23.x, 144.2695041f, -21.64042561f));
            acc3 += exp2f(fmaf(b23.y, 144.2695041f, -21.64042561f));
        }
        // 0.01*ln(acc) + 0.15 = 0.0069314718*log2(acc) + 0.15
        float o0 = fmaf(0.006931472f, log2f(acc0), 0.15f);
        float o1 = fmaf(0.006931472f, log2f(acc1), 0.15f);
        float o2 = fmaf(0.006931472f, log2f(acc2), 0.15f);
        float o3 = fmaf(0.006931472f, log2f(acc3), 0.15f);
        out[(size_t)(b0 + 0) * G_ + g] = o0;
        out[(size_t)(b0 + 1) * G_ + g] = o1;
        out[(size_t)(b0 + 2) * G_ + g] = o2;
        out[(size_t)(b0 + 3) * G_ + g] = o3;
        m = fmaxf(fmaxf(o0, o1), fmaxf(o2, o3));
    }

    // ---- block max -> global atomic (positive floats: int-bit max == float max) ----
    #pragma unroll
    for (int off = 32; off >= 1; off >>= 1)
        m = fmaxf(m, __shfl_down(m, off));
    if ((tid & 63) == 0) red[tid >> 6] = m;
    __syncthreads();
    if (tid == 0) {
        float mm = fmaxf(fmaxf(red[0], red[1]), red[2]);
        atomicMax(wsmax, __float_as_int(mm));
    }
}

// ---------------- conditional global-max normalization --------------------------
__global__ void norm_out(float* __restrict__ out, const int* __restrict__ wsmax, int n4) {
    int i = blockIdx.x * blockDim.x + threadIdx.x;
    float mv = __int_as_float(*wsmax);
    float s  = (mv > 1.0f) ? (1.0f / mv) : 1.0f;
    if (i < n4) {
        float4 v = ((float4*)out)[i];
        v.x *= s; v.y *= s; v.z *= s; v.w *= s;
        ((float4*)out)[i] = v;
    }
}

// ---------------- launcher ------------------------------------------------------
extern "C" void kernel_launch(void* const* d_in, const int* in_sizes, int n_in,
                              void* d_out, int out_size, void* d_ws, size_t ws_size,
                              hipStream_t stream) {
    const float* x   = (const float*)d_in[0];
    const int*   idx = (const int*)d_in[1];
    float* out = (float*)d_out;
    int* wsmax = (int*)d_ws;

    // zero the atomic-max cell (d_ws is re-poisoned 0xAA each replay)
    (void)hipMemsetAsync(wsmax, 0, sizeof(int), stream);

    dim3 grid(NCHUNK, B_ / 4);
    clause_main<<<grid, NTH, 0, stream>>>(x, idx, out, wsmax);

    const int n4 = (B_ * G_) / 4;             // 160,000
    norm_out<<<(n4 + 255) / 256, 256, 0, stream>>>(out, wsmax, n4);
}

// Round 9
// 79.143 us; speedup vs baseline: 1.2743x; 1.1051x over previous
//
#include <hip/hip_runtime.h>
#include <hip/hip_fp16.h>

#define G_   5000
#define B_   128
#define S_   32
#define NTH  320      // 5 waves; GPB/NTH = 98% lane density (R8's 157/192 cost 20%)
#define GPB  313      // ceil(5000/16)
#define NCHUNK 16     // grid (16, 32) = 512 blocks = 2/CU (40KB LDS, VGPR ~160)

union H2F { __half2 h2; float f; };
__device__ __forceinline__ float h2_as_f(__half2 h) { H2F u; u.h2 = h; return u.f; }
__device__ __forceinline__ __half2 f_as_h2(float f) { H2F u; u.f = f; return u.h2; }

// ---------------- main clause evaluation ---------------------------------------
// Block: 320 threads; owns 4 consecutive batch rows (blockIdx.y) and 313 g's
// (blockIdx.x). x rows -> fp16, 4-batch-interleaved in LDS (40,000 B):
// xi[4*i+j] = (half)x[b0+j][i]; one ds_read_b64 serves 4 outputs.
// Measured R5/R8: time tracks wave-gather count at ~62 cyc/gather regardless of
// 2 vs 4 blocks/CU => latency-bound with weak MLP (VGPR_Count was 40!). This
// version force-widens MLP: per 8 s-iters, issue all 32 ds_read_b64 into a
// register array before consuming. launch_bounds(320,2) frees up to 256 VGPRs.
__global__ __launch_bounds__(NTH, 2)
void clause_main(const float* __restrict__ x,
                 const int*  __restrict__ idx,   // harness delivers int64 ref idx as int32
                 float* __restrict__ out,
                 int*   __restrict__ wsmax) {
    __shared__ __half xi[G_ * 4];         // 40,000 B
    __shared__ float red[NTH / 64];

    const int tid = threadIdx.x;
    const int b0  = blockIdx.y * 4;

    // ---- stage 4 x-rows -> fp16, interleaved; ds_write_b128 per 2 columns ----
    const float2* r0 = (const float2*)(x + (size_t)(b0 + 0) * G_);
    const float2* r1 = (const float2*)(x + (size_t)(b0 + 1) * G_);
    const float2* r2 = (const float2*)(x + (size_t)(b0 + 2) * G_);
    const float2* r3 = (const float2*)(x + (size_t)(b0 + 3) * G_);
    float4* xi4 = (float4*)xi;
    for (int i = tid; i < G_ / 2; i += NTH) {   // 2500/320 = 8 iters/thread
        float2 a0 = r0[i], a1 = r1[i], a2 = r2[i], a3 = r3[i];
        float4 w;
        w.x = h2_as_f(__floats2half2_rn(a0.x, a1.x));   // col 2i,   batches 0,1
        w.y = h2_as_f(__floats2half2_rn(a2.x, a3.x));   // col 2i,   batches 2,3
        w.z = h2_as_f(__floats2half2_rn(a0.y, a1.y));   // col 2i+1, batches 0,1
        w.w = h2_as_f(__floats2half2_rn(a2.y, a3.y));   // col 2i+1, batches 2,3
        xi4[i] = w;
    }
    __syncthreads();

    const int g = blockIdx.x * GPB + tid;
    const bool active = (tid < GPB) && (g < G_);
    const float2* xi2 = (const float2*)xi;   // one float2 = 4 halves = 4 batches of col i
    float m = 0.0f;

    if (active) {
        // gamma*lse(body/gamma) = 0.15 + 0.01*ln(sum_s exp(100*body_s - 15))
        // body in (0,1]: term <= e^85 => sum <= 32*e^85 ~ 2.6e38 < FLT_MAX.
        float acc0 = 0.0f, acc1 = 0.0f, acc2 = 0.0f, acc3 = 0.0f;
        const int4* ip = ((const int4*)idx) + (size_t)g * S_;

        #pragma unroll
        for (int so = 0; so < S_; so += 8) {
            // stage 1: 8 idx loads (global, L2-resident)
            int4 id[8];
            #pragma unroll
            for (int j = 0; j < 8; ++j) id[j] = ip[so + j];
            // stage 2: issue all 32 gathers before any consume (64 VGPRs data)
            float2 wv[32];
            #pragma unroll
            for (int j = 0; j < 8; ++j) {
                wv[4 * j + 0] = xi2[id[j].x];
                wv[4 * j + 1] = xi2[id[j].y];
                wv[4 * j + 2] = xi2[id[j].z];
                wv[4 * j + 3] = xi2[id[j].w];
            }
            // stage 3: consume
            #pragma unroll
            for (int j = 0; j < 8; ++j) {
                __half2 lo = __hmul2(__hmul2(f_as_h2(wv[4*j+0].x), f_as_h2(wv[4*j+1].x)),
                                     __hmul2(f_as_h2(wv[4*j+2].x), f_as_h2(wv[4*j+3].x)));
                __half2 hi = __hmul2(__hmul2(f_as_h2(wv[4*j+0].y), f_as_h2(wv[4*j+1].y)),
                                     __hmul2(f_as_h2(wv[4*j+2].y), f_as_h2(wv[4*j+3].y)));
                float2 b01 = __half22float2(lo);
                float2 b23 = __half22float2(hi);
                // exp(100*b-15) = 2^(b*144.269504 - 21.640425)
                acc0 += exp2f(fmaf(b01.x, 144.2695041f, -21.64042561f));
                acc1 += exp2f(fmaf(b01.y, 144.2695041f, -21.64042561f));
                acc2 += exp2f(fmaf(b23.x, 144.2695041f, -21.64042561f));
                acc3 += exp2f(fmaf(b23.y, 144.2695041f, -21.64042561f));
            }
        }
        // 0.01*ln(acc) + 0.15 = 0.0069314718*log2(acc) + 0.15
        float o0 = fmaf(0.006931472f, log2f(acc0), 0.15f);
        float o1 = fmaf(0.006931472f, log2f(acc1), 0.15f);
        float o2 = fmaf(0.006931472f, log2f(acc2), 0.15f);
        float o3 = fmaf(0.006931472f, log2f(acc3), 0.15f);
        out[(size_t)(b0 + 0) * G_ + g] = o0;
        out[(size_t)(b0 + 1) * G_ + g] = o1;
        out[(size_t)(b0 + 2) * G_ + g] = o2;
        out[(size_t)(b0 + 3) * G_ + g] = o3;
        m = fmaxf(fmaxf(o0, o1), fmaxf(o2, o3));
    }

    // ---- block max -> global atomic (positive floats: int-bit max == float max) ----
    #pragma unroll
    for (int off = 32; off >= 1; off >>= 1)
        m = fmaxf(m, __shfl_down(m, off));
    if ((tid & 63) == 0) red[tid >> 6] = m;
    __syncthreads();
    if (tid == 0) {
        float mm = red[0];
        #pragma unroll
        for (int w = 1; w < NTH / 64; ++w) mm = fmaxf(mm, red[w]);
        atomicMax(wsmax, __float_as_int(mm));
    }
}

// ---------------- conditional global-max normalization --------------------------
__global__ void norm_out(float* __restrict__ out, const int* __restrict__ wsmax, int n4) {
    int i = blockIdx.x * blockDim.x + threadIdx.x;
    float mv = __int_as_float(*wsmax);
    float s  = (mv > 1.0f) ? (1.0f / mv) : 1.0f;
    if (i < n4) {
        float4 v = ((float4*)out)[i];
        v.x *= s; v.y *= s; v.z *= s; v.w *= s;
        ((float4*)out)[i] = v;
    }
}

// ---------------- launcher ------------------------------------------------------
extern "C" void kernel_launch(void* const* d_in, const int* in_sizes, int n_in,
                              void* d_out, int out_size, void* d_ws, size_t ws_size,
                              hipStream_t stream) {
    const float* x   = (const float*)d_in[0];
    const int*   idx = (const int*)d_in[1];
    float* out = (float*)d_out;
    int* wsmax = (int*)d_ws;

    // zero the atomic-max cell (d_ws is re-poisoned 0xAA each replay)
    (void)hipMemsetAsync(wsmax, 0, sizeof(int), stream);

    dim3 grid(NCHUNK, B_ / 4);
    clause_main<<<grid, NTH, 0, stream>>>(x, idx, out, wsmax);

    const int n4 = (B_ * G_) / 4;             // 160,000
    norm_out<<<(n4 + 255) / 256, 256, 0, stream>>>(out, wsmax, n4);
}